// Round 13
// baseline (227.248 us; speedup 1.0000x reference)
//
#include <hip/hip_runtime.h>
#include <cmath>

#define LN_EPS 1e-5f

typedef float  f32x4  __attribute__((ext_vector_type(4)));
typedef short  short8 __attribute__((ext_vector_type(8)));
typedef unsigned int uint4v __attribute__((ext_vector_type(4)));

// ws layout (uint4 units):
//   w1tf : 512   (temporal K-slice of w1, k=128..159, B-frag layout, bf16)
//   w2f  : 2048  (B-frag layout, bf16)
//   E1   : 1600  (50 x 128 f32: emb @ w1[:128] table) -- stays in GLOBAL
//   tps  : 5 floats (uniform temporal-LN closed-form sums)
// E1 (round 10): only 50 distinct embedding rows -> emb@w1[:128] is a table.
// ROUND 13: E1 is read from GLOBAL (L1-resident, 25.6 KB), not LDS -- the DS
// pipe is the saturated per-CU resource (round 12: occupancy +22% left
// VALUBusy flat at ~52%); the gather moves to the idle vector-memory path
// and its 1.48M bank-conflict cycles disappear.
#define W1TF_U4 512
#define W2F_U4  2048
#define E1_U4   1600
#define WLDS_U4 2560   // w1tf + w2f staged to LDS

__device__ __forceinline__ unsigned short f32_bf16_rne(float f) {
    union { float f; unsigned u; } v; v.f = f;
    unsigned r = v.u + 0x7FFFu + ((v.u >> 16) & 1u);
    return (unsigned short)(r >> 16);
}

// packed f32->bf16 (RNE), 1 VALU op for 2 elements
__device__ __forceinline__ unsigned cvt_pk_bf16(float lo, float hi) {
    unsigned r;
    asm("v_cvt_pk_bf16_f32 %0, %1, %2" : "=v"(r) : "v"(lo), "v"(hi));
    return r;
}

// exact-erf GELU via Abramowitz&Stegun 7.1.26 (|err| <= 1.5e-7)
__device__ __forceinline__ float gelu_f(float x) {
    float ax = fabsf(x);
    float a  = ax * 0.70710678118654752f;          // |x|/sqrt(2)
    float t  = __builtin_amdgcn_rcpf(fmaf(0.3275911f, a, 1.0f));
    float p  = t * fmaf(t, fmaf(t, fmaf(t, fmaf(t, 1.061405429f, -1.453152027f),
                                        1.421413741f), -0.284496736f), 0.254829592f);
    float e  = __builtin_amdgcn_exp2f(-1.44269504089f * a * a);
    float E  = fmaf(-p, e, 1.0f);                  // erf(|x|/sqrt2)
    return 0.5f * fmaf(ax, E, x);                  // 0.5*(x + |x|*erf)
}

// DPP row-rotate add: sum over the 16-lane DPP row, all lanes get the result.
template<int C>
__device__ __forceinline__ float dpp_radd(float x) {
    int t = __builtin_amdgcn_update_dpp(0, __builtin_bit_cast(int, x), C, 0xF, 0xF, true);
    return x + __builtin_bit_cast(float, t);
}
__device__ __forceinline__ float red16(float x) {
    x = dpp_radd<0x128>(x);   // row_ror:8
    x = dpp_radd<0x124>(x);   // row_ror:4
    x = dpp_radd<0x122>(x);   // row_ror:2
    x = dpp_radd<0x121>(x);   // row_ror:1
    return x;
}

// -------- prep: build w1tf/w2f B-frags (bf16), E1 table (f32), temporal-LN
//          sums. Re-run every call.
__global__ void prep_kernel(const float* __restrict__ w1, const float* __restrict__ w2,
                            const float* __restrict__ emb,
                            const float* __restrict__ tp_w, const float* __restrict__ tp_b,
                            unsigned* __restrict__ ws) {
    const int tid = blockIdx.x * 256 + threadIdx.x;   // 8192 threads
    uint4v* w1tf = (uint4v*)ws;
    uint4v* w2f  = w1tf + W1TF_U4;
    float*  E1   = (float*)(w2f + W2F_U4);
    float*  tps  = E1 + 6400;

    for (int i = tid; i < W1TF_U4; i += 8192) {       // temporal slice frags
        const int lane = i & 63, nt = i >> 6;         // nt 0..7
        const int k0 = 128 + (lane >> 4) * 8, n = nt * 16 + (lane & 15);
        uint4v r;
        #pragma unroll
        for (int j2 = 0; j2 < 4; ++j2) {
            unsigned lo = f32_bf16_rne(w1[(k0 + 2 * j2) * 128 + n]);
            unsigned hi = f32_bf16_rne(w1[(k0 + 2 * j2 + 1) * 128 + n]);
            r[j2] = lo | (hi << 16);
        }
        w1tf[i] = r;
    }
    for (int i = tid; i < W2F_U4; i += 8192) {
        const int lane = i & 63, nt = (i >> 6) & 7, kt = i >> 9;
        const int k0 = kt * 32 + (lane >> 4) * 8, n = nt * 16 + (lane & 15);
        uint4v r;
        #pragma unroll
        for (int j2 = 0; j2 < 4; ++j2) {
            unsigned lo = f32_bf16_rne(w2[(k0 + 2 * j2) * 128 + n]);
            unsigned hi = f32_bf16_rne(w2[(k0 + 2 * j2 + 1) * 128 + n]);
            r[j2] = lo | (hi << 16);
        }
        w2f[i] = r;
    }
    // E1[t][n] = sum_k emb[t][k] * w1[k][n]  (f32 exact; coalesced over n)
    if (tid < 6400) {
        const int t = tid >> 7, n = tid & 127;
        float s = 0.f;
        #pragma unroll 4
        for (int k = 0; k < 128; ++k)
            s = fmaf(emb[t * 128 + k], w1[k * 128 + n], s);
        E1[t * 128 + n] = s;
    }
    if (tid == 0) {                                   // uniform temporal-LN sums
        float Sw = 0.f, Sb = 0.f, Sww = 0.f, Swb = 0.f, Sbb = 0.f;
        for (int j = 0; j < 32; ++j) {
            const float ww = tp_w[j], bb = tp_b[j];
            Sw += ww; Sb += bb; Sww += ww * ww; Swb += ww * bb; Sbb += bb * bb;
        }
        tps[0] = Sw; tps[1] = Sb; tps[2] = Sww; tps[3] = Swb; tps[4] = Sbb;
    }
}

// -------- main: 768 threads = 12 waves; SIX batch rows per block, flattened
//          list of 32-row SUPER-tiles (mt=2): T = sum ceil(len/32) ~= 20,
//          wave w takes st = w, w+12, ... (~1.7 st/wave, same tail as r11).
//
// DS-PIPE DIET (round 13): the per-CU LDS pipe was the 50%-busy shared
// bottleneck (round 12). Cuts: (a) E1 gathers from GLOBAL (vmem pipe, L1);
// (b) mt=2 amortizes GEMM1/GEMM2 B-frag + tcoef LDS reads over 2 m-tiles --
// GEMM2's 32 x ds_read_b128 now serves 64 rows of output via dual a2 slots;
// (c) single atomic-pool set per super-tile. Net ~-45% DS cycles per row.
//
// REGISTER DISCIPLINE (rounds 2-5,7): (768,3) = 170-reg budget. Peak window
// ~72 arch + 64 AGPR (acc[2] or acc2[2]) ~= 136. Phases strictly serial;
// coefficients in LDS; empty-asm fences only (per-wave DS pipe in-order).
// SPILL TRIPWIRE: WRITE_SIZE > 50 MB => revert to round-11 config.
__global__ __launch_bounds__(768, 3) void encoder_mfma(
    const int*   __restrict__ tids,  const float* __restrict__ dates,
    const int*   __restrict__ lengths,
    const float* __restrict__ tp_w,  const float* __restrict__ tp_b,
    const float* __restrict__ tp_lnw,const float* __restrict__ tp_lnb,
    const float* __restrict__ b1,    const float* __restrict__ ln1w, const float* __restrict__ ln1b,
    const float* __restrict__ b2,    const float* __restrict__ ln2w, const float* __restrict__ ln2b,
    const unsigned* __restrict__ ws, float* __restrict__ out,
    int B, int L)
{
    __shared__ __align__(16) uint4v wlds[WLDS_U4];                // 40 KB: w1tf|w2f
    // per-wave C->A transpose scratch, TWO m-tile slots: [wave][mt][kt2][row][j]
    __shared__ __align__(16) unsigned short a2[12][2][4][64][8];  // 96 KB
    __shared__ float poolrow[6][128];                             // 3 KB (atomic)
    __shared__ __align__(16) f32x4 tcoef[32];    // {tp_w, tp_b, tp_lnw, tp_lnb}
    __shared__ __align__(16) f32x4 ecoef1[128];  // {b1, ln1w, ln1b, -}
    __shared__ __align__(16) f32x4 ecoef2[128];  // {b2, ln2w, ln2b, -}

    const int tid = threadIdx.x;
    const int lane = tid & 63, w = tid >> 6;          // w in 0..11
    const int c = lane & 15, g = lane >> 4;
    const int b0 = blockIdx.x * 6;

    // ---- stage weights into LDS; zero pool accumulators ----
    for (int i = tid; i < WLDS_U4; i += 768)
        wlds[i] = ((const uint4v*)ws)[i];
    poolrow[tid >> 7][tid & 127] = 0.f;               // 768 = 6*128 exactly

    const float* E1g = (const float*)((const uint4v*)ws + WLDS_U4);
    const float* tps = E1g + 6400;

    if (tid < 32)  tcoef[tid]  = (f32x4){tp_w[tid], tp_b[tid], tp_lnw[tid], tp_lnb[tid]};
    if (tid < 128) {
        ecoef1[tid] = (f32x4){b1[tid], ln1w[tid], ln1b[tid], 0.f};
        ecoef2[tid] = (f32x4){b2[tid], ln2w[tid], ln2b[tid], 0.f};
    }
    __syncthreads();

    const float Sw = tps[0], Sb = tps[1], Sww = tps[2], Swb = tps[3], Sbb = tps[4];

    // flattened 32-row super-tile list over the block's 6 rows
    int lenA[6];
    #pragma unroll
    for (int i = 0; i < 6; ++i)
        lenA[i] = (b0 + i < B) ? min(max(lengths[b0 + i], 0), L) : 0;
    const int n0 = (lenA[0] + 31) >> 5, n1 = (lenA[1] + 31) >> 5, n2 = (lenA[2] + 31) >> 5;
    const int n3 = (lenA[3] + 31) >> 5, n4 = (lenA[4] + 31) >> 5, n5 = (lenA[5] + 31) >> 5;
    const int cum1 = n0, cum2 = cum1 + n1, cum3 = cum2 + n2;
    const int cum4 = cum3 + n3, cum5 = cum4 + n4, T = cum5 + n5;
    const int len0 = lenA[0], len1 = lenA[1], len2 = lenA[2];
    const int len3 = lenA[3], len4 = lenA[4], len5 = lenA[5];

    const int srl = lane ^ ((lane >> 3) & 3);          // swizzled GEMM2 read row

    for (int st = w; st < T; st += 12) {
        // wave-uniform (row, local super-tile) from flattened index
        int row, tl, lenr;
        if      (st >= cum5) { row = 5; tl = st - cum5; lenr = len5; }
        else if (st >= cum4) { row = 4; tl = st - cum4; lenr = len4; }
        else if (st >= cum3) { row = 3; tl = st - cum3; lenr = len3; }
        else if (st >= cum2) { row = 2; tl = st - cum2; lenr = len2; }
        else if (st >= cum1) { row = 1; tl = st - cum1; lenr = len1; }
        else                 { row = 0; tl = st;        lenr = len0; }
        const int R0 = tl << 5;
        const bool amt1 = (R0 + 16) < lenr;            // wave-uniform
        const long base = (long)(b0 + row) * L;

        // per-mt ids (C-layout rows 4g+r) and dates
        int idr0[4], idr1[4];
        #pragma unroll
        for (int r = 0; r < 4; ++r)
            idr0[r] = tids[base + min(R0 + 4 * g + r, L - 1)];
        if (amt1) {
            #pragma unroll
            for (int r = 0; r < 4; ++r)
                idr1[r] = tids[base + min(R0 + 16 + 4 * g + r, L - 1)];
        }
        const float dn0 = dates[base + min(R0 + c,      L - 1)] * (1.f / 1825.f);
        const float dn1 = dates[base + min(R0 + 16 + c, L - 1)] * (1.f / 1825.f);

        // ---- GEMM1 acc init: E1 gather from GLOBAL (L1-resident table) ----
        f32x4 acc[2][8];
        #pragma unroll
        for (int r = 0; r < 4; ++r) {
            const int e1b = idr0[r] * 128 + c;
            #pragma unroll
            for (int nt = 0; nt < 8; ++nt)
                acc[0][nt][r] = E1g[e1b + nt * 16];
        }
        if (amt1) {
            #pragma unroll
            for (int r = 0; r < 4; ++r) {
                const int e1b = idr1[r] * 128 + c;
                #pragma unroll
                for (int nt = 0; nt < 8; ++nt)
                    acc[1][nt][r] = E1g[e1b + nt * 16];
            }
        }

        // temporal A-frags (row = c, k-chunk = g*8..g*8+7); tcoef read ONCE
        short8 tfrag[2];
        {
            const int j0 = g * 8;
            f32x4 tc[8];
            #pragma unroll
            for (int jj = 0; jj < 8; ++jj) tc[jj] = tcoef[j0 + jj];
            #pragma unroll
            for (int mt = 0; mt < 2; ++mt) {
                const float d  = mt ? dn1 : dn0;
                const float tm = fmaf(d, Sw, Sb) * (1.f / 32.f);
                float tv = fmaf(d * d, Sww, fmaf(2.f * d, Swb, Sbb)) * (1.f / 32.f) - tm * tm;
                const float trs = rsqrtf(fmaxf(tv, 0.f) + LN_EPS);
                uint4v r;
                #pragma unroll
                for (int j2 = 0; j2 < 4; ++j2) {
                    const f32x4 t0 = tc[2*j2], t1 = tc[2*j2 + 1];
                    const float y0 = fmaf((fmaf(d, t0[0], t0[1]) - tm) * trs, t0[2], t0[3]);
                    const float y1 = fmaf((fmaf(d, t1[0], t1[1]) - tm) * trs, t1[2], t1[3]);
                    r[j2] = cvt_pk_bf16(gelu_f(y0), gelu_f(y1));
                }
                union { uint4v u; short8 s; } cv; cv.u = r;
                tfrag[mt] = cv.s;
            }
        }

        // ---- GEMM1: temporal K=32 slice; bf read once, serves both mt ----
        __builtin_amdgcn_s_setprio(1);
        #pragma unroll
        for (int nt = 0; nt < 8; ++nt) {
            const short8 bf = ((const short8*)wlds)[nt * 64 + lane];
            acc[0][nt] = __builtin_amdgcn_mfma_f32_16x16x32_bf16(tfrag[0], bf, acc[0][nt], 0, 0, 0);
            if (amt1)
                acc[1][nt] = __builtin_amdgcn_mfma_f32_16x16x32_bf16(tfrag[1], bf, acc[1][nt], 0, 0, 0);
        }
        __builtin_amdgcn_s_setprio(0);

        // ------- epilogue 1 (both mt, e1 read once) -> a2 slots 0/1 -------
        {
            f32x4 e1[8];
            #pragma unroll
            for (int nt = 0; nt < 8; ++nt) e1[nt] = ecoef1[nt * 16 + c];
            #pragma unroll
            for (int mt = 0; mt < 2; ++mt) {
                if (mt && !amt1) continue;             // wave-uniform skip
                #pragma unroll
                for (int r = 0; r < 4; ++r) {
                    float v[8], s = 0.f, q = 0.f;
                    #pragma unroll
                    for (int nt = 0; nt < 8; ++nt) {
                        v[nt] = acc[mt][nt][r] + e1[nt][0];
                        s += v[nt]; q = fmaf(v[nt], v[nt], q);
                    }
                    s = red16(s); q = red16(q);
                    const float mean = s * (1.f / 128.f);
                    const float var  = fmaxf(q * (1.f / 128.f) - mean * mean, 0.f);
                    const float rstd = rsqrtf(var + LN_EPS);
                    const int mrow = 4 * g + r;
                    #pragma unroll
                    for (int n2 = 0; n2 < 4; ++n2) {
                        const float y0 = gelu_f(fmaf((v[2*n2]   - mean) * rstd, e1[2*n2][1],   e1[2*n2][2]));
                        const float y1 = gelu_f(fmaf((v[2*n2+1] - mean) * rstd, e1[2*n2+1][1], e1[2*n2+1][2]));
                        const unsigned pk = cvt_pk_bf16(y0, y1);
                        {
                            const int kcol  = (2*n2) * 16 + c;
                            const int row64 = ((kcol >> 3) & 3) * 16 + mrow;
                            const int srow  = row64 ^ ((row64 >> 3) & 3);
                            a2[w][mt][kcol >> 5][srow][kcol & 7] = (unsigned short)(pk & 0xffffu);
                        }
                        {
                            const int kcol  = (2*n2+1) * 16 + c;
                            const int row64 = ((kcol >> 3) & 3) * 16 + mrow;
                            const int srow  = row64 ^ ((row64 >> 3) & 3);
                            a2[w][mt][kcol >> 5][srow][kcol & 7] = (unsigned short)(pk >> 16);
                        }
                    }
                }
            }
        }

        asm volatile("" ::: "memory");                 // order a2 W->R (DS in-order)

        // ---- GEMM2 dual: bf read ONCE per (kt2,nt), serves both a2 slots ----
        f32x4 acc2[2][8];
        #pragma unroll
        for (int mt = 0; mt < 2; ++mt)
            #pragma unroll
            for (int nt = 0; nt < 8; ++nt) acc2[mt][nt] = (f32x4){0.f, 0.f, 0.f, 0.f};
        __builtin_amdgcn_s_setprio(1);
        #pragma unroll
        for (int kt2 = 0; kt2 < 4; ++kt2) {
            short8 af0, af1;
            __builtin_memcpy(&af0, &a2[w][0][kt2][srl][0], 16);
            if (amt1) __builtin_memcpy(&af1, &a2[w][1][kt2][srl][0], 16);
            #pragma unroll
            for (int nt = 0; nt < 8; ++nt) {
                const short8 bf = ((const short8*)(wlds + W1TF_U4))[(kt2 * 8 + nt) * 64 + lane];
                acc2[0][nt] = __builtin_amdgcn_mfma_f32_16x16x32_bf16(af0, bf, acc2[0][nt], 0, 0, 0);
                if (amt1)
                    acc2[1][nt] = __builtin_amdgcn_mfma_f32_16x16x32_bf16(af1, bf, acc2[1][nt], 0, 0, 0);
            }
        }
        __builtin_amdgcn_s_setprio(0);

        asm volatile("" ::: "memory");                 // order a2 R -> next st W

        // ---- epilogue 2 (both mt, e2 once) -> ptile -> ONE atomic set ----
        {
            f32x4 e2[8];
            #pragma unroll
            for (int nt = 0; nt < 8; ++nt) e2[nt] = ecoef2[nt * 16 + c];
            float ptile[8];
            #pragma unroll
            for (int nt = 0; nt < 8; ++nt) ptile[nt] = 0.f;
            #pragma unroll
            for (int mt = 0; mt < 2; ++mt) {
                if (mt && !amt1) continue;
                #pragma unroll
                for (int r = 0; r < 4; ++r) {
                    float v[8], s = 0.f, q = 0.f;
                    #pragma unroll
                    for (int nt = 0; nt < 8; ++nt) {
                        v[nt] = acc2[mt][nt][r] + e2[nt][0];
                        s += v[nt]; q = fmaf(v[nt], v[nt], q);
                    }
                    s = red16(s); q = red16(q);
                    const float mean = s * (1.f / 128.f);
                    const float var  = fmaxf(q * (1.f / 128.f) - mean * mean, 0.f);
                    const float rstd = rsqrtf(var + LN_EPS);
                    const float msk = ((R0 + mt * 16 + 4 * g + r) < lenr) ? 1.f : 0.f;
                    #pragma unroll
                    for (int nt = 0; nt < 8; ++nt) {
                        const float y = fmaf((v[nt] - mean) * rstd, e2[nt][1], e2[nt][2]);
                        ptile[nt] = fmaf(y, msk, ptile[nt]);
                    }
                }
            }
            // reduce over g (2 shfl) then one LDS atomic per nt from g==0
            #pragma unroll
            for (int nt = 0; nt < 8; ++nt) {
                float tv = ptile[nt];
                tv += __shfl_xor(tv, 16);
                tv += __shfl_xor(tv, 32);
                ptile[nt] = tv;
            }
            if (g == 0) {
                #pragma unroll
                for (int nt = 0; nt < 8; ++nt)
                    atomicAdd(&poolrow[row][nt * 16 + c], ptile[nt]);
            }
        }
    }

    __syncthreads();
    {
        const int r6  = tid >> 7;                      // which row of the six
        const int col = tid & 127;
        const int bo  = b0 + r6;
        if (bo < B) {
            const int lenb = min(max(lengths[bo], 0), L);
            out[bo * 128 + col] = (lenb > 0) ? poolrow[r6][col] / (float)lenb : 0.f;
        }
    }
}

extern "C" void kernel_launch(void* const* d_in, const int* in_sizes, int n_in,
                              void* d_out, int out_size, void* d_ws, size_t ws_size,
                              hipStream_t stream) {
    const int*   tids    = (const int*)  d_in[0];
    const float* dates   = (const float*)d_in[1];
    const int*   lengths = (const int*)  d_in[2];
    const float* emb     = (const float*)d_in[3];
    const float* tp_w    = (const float*)d_in[4];
    const float* tp_b    = (const float*)d_in[5];
    const float* tp_lnw  = (const float*)d_in[6];
    const float* tp_lnb  = (const float*)d_in[7];
    const float* w1      = (const float*)d_in[8];
    const float* b1      = (const float*)d_in[9];
    const float* ln1w    = (const float*)d_in[10];
    const float* ln1b    = (const float*)d_in[11];
    const float* w2      = (const float*)d_in[12];
    const float* b2      = (const float*)d_in[13];
    const float* ln2w    = (const float*)d_in[14];
    const float* ln2b    = (const float*)d_in[15];
    float* out = (float*)d_out;

    const int B = in_sizes[2];
    const int L = in_sizes[0] / B;

    hipLaunchKernelGGL(prep_kernel, dim3(32), dim3(256), 0, stream,
                       w1, w2, emb, tp_w, tp_b, (unsigned*)d_ws);
    hipLaunchKernelGGL(encoder_mfma, dim3((B + 5) / 6), dim3(768), 0, stream,
                       tids, dates, lengths, tp_w, tp_b, tp_lnw, tp_lnb,
                       b1, ln1w, ln1b, b2, ln2w, ln2b,
                       (const unsigned*)d_ws, out, B, L);
}

// Round 14
// 195.210 us; speedup vs baseline: 1.1641x; 1.1641x over previous
//
#include <hip/hip_runtime.h>
#include <cmath>

#define LN_EPS 1e-5f

typedef float  f32x4  __attribute__((ext_vector_type(4)));
typedef short  short8 __attribute__((ext_vector_type(8)));
typedef unsigned int uint4v __attribute__((ext_vector_type(4)));

// ws layout (uint4 units):
//   w1tf : 512   (temporal K-slice of w1, k=128..159, B-frag layout, bf16)
//   w2f  : 2048  (B-frag layout, bf16)
//   E1   : 1650  (50 x 132 f32: emb @ w1[:128] + b1 table, 128 cols + 4 pad)
//   tps  : 5 floats (uniform temporal-LN closed-form sums)
// E1 (round 10): only 50 distinct embedding rows -> emb@w1[:128] is a table
// (exact f32). ROUND 14: b1 is folded into E1 (it is the MFMA C-init, added
// exactly once), killing 32 adds/tile in epilogue 1.
#define W1TF_U4 512
#define W2F_U4  2048
#define E1_U4   1650
#define WLDS_U4 2560   // w1tf + w2f staged to LDS

__device__ __forceinline__ unsigned short f32_bf16_rne(float f) {
    union { float f; unsigned u; } v; v.f = f;
    unsigned r = v.u + 0x7FFFu + ((v.u >> 16) & 1u);
    return (unsigned short)(r >> 16);
}

// packed f32->bf16 (RNE), 1 VALU op for 2 elements
__device__ __forceinline__ unsigned cvt_pk_bf16(float lo, float hi) {
    unsigned r;
    asm("v_cvt_pk_bf16_f32 %0, %1, %2" : "=v"(r) : "v"(lo), "v"(hi));
    return r;
}

// GELU, tanh/sigmoid form (round 14): x * sigmoid(1.5957691*(x+0.044715x^3)).
// |err| vs exact-erf GELU <= ~3e-4 absolute (abs tolerance headroom >= 0.01:
// round 1 passed at absmax 0.0254). 6 VALU + 2 trans vs 12+2 for the A&S-erf
// form -- the kernel is VALU-work bound (r12: +waves flat; r13: -DS negative),
// so instruction-count reduction in the GELU-heavy epilogue is the lever.
__device__ __forceinline__ float gelu_f(float x) {
    const float arg = x * fmaf(x * x, 0.044715f, 1.0f);   // x + 0.044715 x^3
    const float e   = __builtin_amdgcn_exp2f(arg * -2.302258f); // exp(-1.59577*arg)
    const float r   = __builtin_amdgcn_rcpf(e + 1.0f);    // sigmoid
    return x * r;
}

// DPP row-rotate add: sum over the 16-lane DPP row, all lanes get the result.
template<int C>
__device__ __forceinline__ float dpp_radd(float x) {
    int t = __builtin_amdgcn_update_dpp(0, __builtin_bit_cast(int, x), C, 0xF, 0xF, true);
    return x + __builtin_bit_cast(float, t);
}
__device__ __forceinline__ float red16(float x) {
    x = dpp_radd<0x128>(x);   // row_ror:8
    x = dpp_radd<0x124>(x);   // row_ror:4
    x = dpp_radd<0x122>(x);   // row_ror:2
    x = dpp_radd<0x121>(x);   // row_ror:1
    return x;
}

// -------- prep: build w1tf/w2f B-frags (bf16), E1 table (f32, +b1),
//          temporal-LN sums. Re-run every call.
__global__ void prep_kernel(const float* __restrict__ w1, const float* __restrict__ w2,
                            const float* __restrict__ emb, const float* __restrict__ b1,
                            const float* __restrict__ tp_w, const float* __restrict__ tp_b,
                            unsigned* __restrict__ ws) {
    const int tid = blockIdx.x * 256 + threadIdx.x;   // 8192 threads
    uint4v* w1tf = (uint4v*)ws;
    uint4v* w2f  = w1tf + W1TF_U4;
    float*  E1   = (float*)(w2f + W2F_U4);
    float*  tps  = E1 + 6600;

    for (int i = tid; i < W1TF_U4; i += 8192) {       // temporal slice frags
        const int lane = i & 63, nt = i >> 6;         // nt 0..7
        const int k0 = 128 + (lane >> 4) * 8, n = nt * 16 + (lane & 15);
        uint4v r;
        #pragma unroll
        for (int j2 = 0; j2 < 4; ++j2) {
            unsigned lo = f32_bf16_rne(w1[(k0 + 2 * j2) * 128 + n]);
            unsigned hi = f32_bf16_rne(w1[(k0 + 2 * j2 + 1) * 128 + n]);
            r[j2] = lo | (hi << 16);
        }
        w1tf[i] = r;
    }
    for (int i = tid; i < W2F_U4; i += 8192) {
        const int lane = i & 63, nt = (i >> 6) & 7, kt = i >> 9;
        const int k0 = kt * 32 + (lane >> 4) * 8, n = nt * 16 + (lane & 15);
        uint4v r;
        #pragma unroll
        for (int j2 = 0; j2 < 4; ++j2) {
            unsigned lo = f32_bf16_rne(w2[(k0 + 2 * j2) * 128 + n]);
            unsigned hi = f32_bf16_rne(w2[(k0 + 2 * j2 + 1) * 128 + n]);
            r[j2] = lo | (hi << 16);
        }
        w2f[i] = r;
    }
    // E1[t][n] = b1[n] + sum_k emb[t][k] * w1[k][n]  (f32 exact)
    if (tid < 6400) {
        const int t = tid >> 7, n = tid & 127;
        float s = b1[n];
        #pragma unroll 4
        for (int k = 0; k < 128; ++k)
            s = fmaf(emb[t * 128 + k], w1[k * 128 + n], s);
        E1[t * 132 + n] = s;
    }
    if (tid == 0) {                                   // uniform temporal-LN sums
        float Sw = 0.f, Sb = 0.f, Sww = 0.f, Swb = 0.f, Sbb = 0.f;
        for (int j = 0; j < 32; ++j) {
            const float ww = tp_w[j], bb = tp_b[j];
            Sw += ww; Sb += bb; Sww += ww * ww; Swb += ww * bb; Sbb += bb * bb;
        }
        tps[0] = Sw; tps[1] = Sb; tps[2] = Sww; tps[3] = Swb; tps[4] = Sbb;
    }
}

// -------- main: 768 threads = 12 waves; THREE batch rows per block with a
//          FLATTENED tile list (round 11, the best-measured config): tiles of
//          all 3 rows form one list of length T; wave w takes t = w, w+12, ...
//          Pools are three NAMED register arrays selected by a wave-uniform
//          branch; per-wave partials -> poolbuf[3][12][128].
//
// REGIME (rounds 12/13 falsifications): +waves (r12) flat, -DS (r13) negative
// => VALU-work-stream bound. r14 attacks work count (gelu, b1-fold) on the
// r11 base. Do NOT re-add mt=2 or move E1 off LDS.
//
// REGISTER DISCIPLINE (rounds 2-5,7): (768,3) = 170-reg budget; r11 measured
// 72 arch + 64 acc, no spill. Phases strictly serial per tile; coefficients
// in LDS; empty-asm fences only (per-wave DS pipe is in-order).
// SPILL TRIPWIRE: WRITE_SIZE > 50 MB => revert.
__global__ __launch_bounds__(768, 3) void encoder_mfma(
    const int*   __restrict__ tids,  const float* __restrict__ dates,
    const int*   __restrict__ lengths,
    const float* __restrict__ tp_w,  const float* __restrict__ tp_b,
    const float* __restrict__ tp_lnw,const float* __restrict__ tp_lnb,
    const float* __restrict__ b1,    const float* __restrict__ ln1w, const float* __restrict__ ln1b,
    const float* __restrict__ b2,    const float* __restrict__ ln2w, const float* __restrict__ ln2b,
    const unsigned* __restrict__ ws, float* __restrict__ out,
    int B, int L)
{
    __shared__ __align__(16) uint4v wlds[WLDS_U4];                // 40 KB: w1tf|w2f
    __shared__ __align__(16) float  E1lds[6600];                  // 26.4 KB
    // per-wave C->A transpose scratch (single m-tile): [wave][kt2][row64][j]
    __shared__ __align__(16) unsigned short a2[12][4][64][8];     // 48 KB
    __shared__ float poolbuf[3][12][128];                         // 18 KB
    __shared__ __align__(16) f32x4 tcoef[32];    // {tp_w, tp_b, tp_lnw, tp_lnb}
    __shared__ __align__(16) f32x4 ecoef1[128];  // {-, ln1w, ln1b, -} (b1 in E1)
    __shared__ __align__(16) f32x4 ecoef2[128];  // {b2, ln2w, ln2b, -}

    const int tid = threadIdx.x;
    const int lane = tid & 63, w = tid >> 6;          // w in 0..11
    const int c = lane & 15, g = lane >> 4;
    const int b0 = blockIdx.x * 3;

    // ---- stage weights + E1 into LDS ----
    for (int i = tid; i < WLDS_U4; i += 768)
        wlds[i] = ((const uint4v*)ws)[i];
    for (int i = tid; i < E1_U4; i += 768)
        ((uint4v*)E1lds)[i] = ((const uint4v*)ws)[WLDS_U4 + i];

    const float* tps = (const float*)((const uint4v*)ws + WLDS_U4 + E1_U4);

    if (tid < 32)  tcoef[tid]  = (f32x4){tp_w[tid], tp_b[tid], tp_lnw[tid], tp_lnb[tid]};
    if (tid < 128) {
        ecoef1[tid] = (f32x4){0.f, ln1w[tid], ln1b[tid], 0.f};
        ecoef2[tid] = (f32x4){b2[tid], ln2w[tid], ln2b[tid], 0.f};
    }
    __syncthreads();

    const float Sw = tps[0], Sb = tps[1], Sww = tps[2], Swb = tps[3], Sbb = tps[4];

    // flattened tile list over the block's 3 rows
    const int len0 = (b0 + 0 < B) ? min(max(lengths[b0 + 0], 0), L) : 0;
    const int len1 = (b0 + 1 < B) ? min(max(lengths[b0 + 1], 0), L) : 0;
    const int len2 = (b0 + 2 < B) ? min(max(lengths[b0 + 2], 0), L) : 0;
    const int nt0 = (len0 + 15) >> 4, nt1 = (len1 + 15) >> 4, nt2 = (len2 + 15) >> 4;
    const int cum1 = nt0, cum2 = nt0 + nt1, T = cum2 + nt2;

    float pool0[8], pool1[8], pool2[8];
    #pragma unroll
    for (int nt = 0; nt < 8; ++nt) { pool0[nt] = 0.f; pool1[nt] = 0.f; pool2[nt] = 0.f; }
    const int srl = lane ^ ((lane >> 3) & 3);          // swizzled GEMM2 read row

    for (int t = w; t < T; t += 12) {
        // wave-uniform (row, local tile) from flattened index
        const int row  = (t >= cum2) ? 2 : ((t >= cum1) ? 1 : 0);
        const int tl   = t - ((row == 2) ? cum2 : ((row == 1) ? cum1 : 0));
        const int bb   = b0 + row;
        const int lenr = (row == 2) ? len2 : ((row == 1) ? len1 : len0);
        const int R0   = tl << 4;
        const long base = (long)bb * L;

        const int pc = min(R0 + c, L - 1);
        const float d = dates[base + pc] * (1.f / 1825.f);
        // ids for this lane's C-layout rows (4g+r); group-uniform broadcast loads
        int idr[4];
        #pragma unroll
        for (int r = 0; r < 4; ++r)
            idr[r] = tids[base + min(R0 + 4 * g + r, L - 1)];

        // temporal A-frag (row = c, k-chunk = g*8..g*8+7); coeffs from LDS
        short8 tfrag;
        {
            const float tm = fmaf(d, Sw, Sb) * (1.f / 32.f);
            float tv = fmaf(d * d, Sww, fmaf(2.f * d, Swb, Sbb)) * (1.f / 32.f) - tm * tm;
            const float trs = rsqrtf(fmaxf(tv, 0.f) + LN_EPS);
            const int j0 = g * 8;
            uint4v r;
            #pragma unroll
            for (int j2 = 0; j2 < 4; ++j2) {
                const f32x4 t0 = tcoef[j0 + 2*j2];
                const f32x4 t1 = tcoef[j0 + 2*j2 + 1];
                const float y0 = fmaf((fmaf(d, t0[0], t0[1]) - tm) * trs, t0[2], t0[3]);
                const float y1 = fmaf((fmaf(d, t1[0], t1[1]) - tm) * trs, t1[2], t1[3]);
                r[j2] = cvt_pk_bf16(gelu_f(y0), gelu_f(y1));
            }
            union { uint4v u; short8 s; } cv; cv.u = r;
            tfrag = cv.s;
        }

        // ---- GEMM1: acc = E1 gather (emb@w1+b1 table) + temporal K=32 MFMA ----
        f32x4 acc[8];
        #pragma unroll
        for (int r = 0; r < 4; ++r) {
            const int e1base = idr[r] * 132 + c;
            #pragma unroll
            for (int nt = 0; nt < 8; ++nt)
                acc[nt][r] = E1lds[e1base + nt * 16];
        }
        __builtin_amdgcn_s_setprio(1);
        #pragma unroll
        for (int nt = 0; nt < 8; ++nt) {
            const short8 bf = ((const short8*)wlds)[nt * 64 + lane];
            acc[nt] = __builtin_amdgcn_mfma_f32_16x16x32_bf16(tfrag, bf, acc[nt], 0, 0, 0);
        }
        __builtin_amdgcn_s_setprio(0);

        // ------- epilogue 1: LN1 (DPP), GELU -> bf16 a2[w] (swizzled) -------
        {
            f32x4 e1[8];
            #pragma unroll
            for (int nt = 0; nt < 8; ++nt) e1[nt] = ecoef1[nt * 16 + c];
            #pragma unroll
            for (int r = 0; r < 4; ++r) {
                float v[8], s = 0.f, q = 0.f;
                #pragma unroll
                for (int nt = 0; nt < 8; ++nt) {
                    v[nt] = acc[nt][r];                // b1 already in E1
                    s += v[nt]; q = fmaf(v[nt], v[nt], q);
                }
                s = red16(s); q = red16(q);
                const float mean = s * (1.f / 128.f);
                const float var  = fmaxf(q * (1.f / 128.f) - mean * mean, 0.f);
                const float rstd = rsqrtf(var + LN_EPS);
                const int mrow = 4 * g + r;
                #pragma unroll
                for (int n2 = 0; n2 < 4; ++n2) {
                    const float y0 = gelu_f(fmaf((v[2*n2]   - mean) * rstd, e1[2*n2][1],   e1[2*n2][2]));
                    const float y1 = gelu_f(fmaf((v[2*n2+1] - mean) * rstd, e1[2*n2+1][1], e1[2*n2+1][2]));
                    const unsigned pk = cvt_pk_bf16(y0, y1);
                    {
                        const int kcol  = (2*n2) * 16 + c;
                        const int row64 = ((kcol >> 3) & 3) * 16 + mrow;
                        const int srow  = row64 ^ ((row64 >> 3) & 3);
                        a2[w][kcol >> 5][srow][kcol & 7] = (unsigned short)(pk & 0xffffu);
                    }
                    {
                        const int kcol  = (2*n2+1) * 16 + c;
                        const int row64 = ((kcol >> 3) & 3) * 16 + mrow;
                        const int srow  = row64 ^ ((row64 >> 3) & 3);
                        a2[w][kcol >> 5][srow][kcol & 7] = (unsigned short)(pk >> 16);
                    }
                }
            }
        }

        asm volatile("" ::: "memory");                 // order a2 W->R (DS in-order)

        // ---------------- GEMM2: a2[w] @ w2f(LDS) ----------------
        f32x4 acc2[8];
        #pragma unroll
        for (int nt = 0; nt < 8; ++nt) acc2[nt] = (f32x4){0.f, 0.f, 0.f, 0.f};
        __builtin_amdgcn_s_setprio(1);
        #pragma unroll
        for (int kt2 = 0; kt2 < 4; ++kt2) {
            short8 af;
            __builtin_memcpy(&af, &a2[w][kt2][srl][0], 16);
            #pragma unroll
            for (int nt = 0; nt < 8; ++nt) {
                const short8 bf = ((const short8*)(wlds + W1TF_U4))[(kt2 * 8 + nt) * 64 + lane];
                acc2[nt] = __builtin_amdgcn_mfma_f32_16x16x32_bf16(af, bf, acc2[nt], 0, 0, 0);
            }
        }
        __builtin_amdgcn_s_setprio(0);

        asm volatile("" ::: "memory");                 // order a2 R -> next tile W

        // ------- epilogue 2: +b2, LN2, mask -> per-tile pool, then bank it -------
        {
            f32x4 e2[8];
            #pragma unroll
            for (int nt = 0; nt < 8; ++nt) e2[nt] = ecoef2[nt * 16 + c];
            float ptile[8];
            #pragma unroll
            for (int nt = 0; nt < 8; ++nt) ptile[nt] = 0.f;
            #pragma unroll
            for (int r = 0; r < 4; ++r) {
                float v[8], s = 0.f, q = 0.f;
                #pragma unroll
                for (int nt = 0; nt < 8; ++nt) {
                    v[nt] = acc2[nt][r] + e2[nt][0];
                    s += v[nt]; q = fmaf(v[nt], v[nt], q);
                }
                s = red16(s); q = red16(q);
                const float mean = s * (1.f / 128.f);
                const float var  = fmaxf(q * (1.f / 128.f) - mean * mean, 0.f);
                const float rstd = rsqrtf(var + LN_EPS);
                const float msk = ((R0 + 4 * g + r) < lenr) ? 1.f : 0.f;
                #pragma unroll
                for (int nt = 0; nt < 8; ++nt) {
                    const float y = fmaf((v[nt] - mean) * rstd, e2[nt][1], e2[nt][2]);
                    ptile[nt] = fmaf(y, msk, ptile[nt]);
                }
            }
            // bank into the wave-uniform row's named pool (no runtime indexing)
            if (row == 0) {
                #pragma unroll
                for (int nt = 0; nt < 8; ++nt) pool0[nt] += ptile[nt];
            } else if (row == 1) {
                #pragma unroll
                for (int nt = 0; nt < 8; ++nt) pool1[nt] += ptile[nt];
            } else {
                #pragma unroll
                for (int nt = 0; nt < 8; ++nt) pool2[nt] += ptile[nt];
            }
        }
    }

    // wave-level pool reduce (over g groups), then cross-wave combine in LDS
    #pragma unroll
    for (int nt = 0; nt < 8; ++nt) {
        float t0 = pool0[nt]; t0 += __shfl_xor(t0, 16); t0 += __shfl_xor(t0, 32); pool0[nt] = t0;
        float t1 = pool1[nt]; t1 += __shfl_xor(t1, 16); t1 += __shfl_xor(t1, 32); pool1[nt] = t1;
        float t2 = pool2[nt]; t2 += __shfl_xor(t2, 16); t2 += __shfl_xor(t2, 32); pool2[nt] = t2;
    }
    if (g == 0) {
        #pragma unroll
        for (int nt = 0; nt < 8; ++nt) {
            poolbuf[0][w][nt * 16 + c] = pool0[nt];
            poolbuf[1][w][nt * 16 + c] = pool1[nt];
            poolbuf[2][w][nt * 16 + c] = pool2[nt];
        }
    }
    __syncthreads();
    if (tid < 384) {
        const int r3  = tid >> 7;                      // which row of the triple
        const int col = tid & 127;
        const int bo  = b0 + r3;
        if (bo < B) {
            const int lenb = min(max(lengths[bo], 0), L);
            float s = 0.f;
            #pragma unroll
            for (int k = 0; k < 12; ++k) s += poolbuf[r3][k][col];
            out[bo * 128 + col] = (lenb > 0) ? s / (float)lenb : 0.f;
        }
    }
}

extern "C" void kernel_launch(void* const* d_in, const int* in_sizes, int n_in,
                              void* d_out, int out_size, void* d_ws, size_t ws_size,
                              hipStream_t stream) {
    const int*   tids    = (const int*)  d_in[0];
    const float* dates   = (const float*)d_in[1];
    const int*   lengths = (const int*)  d_in[2];
    const float* emb     = (const float*)d_in[3];
    const float* tp_w    = (const float*)d_in[4];
    const float* tp_b    = (const float*)d_in[5];
    const float* tp_lnw  = (const float*)d_in[6];
    const float* tp_lnb  = (const float*)d_in[7];
    const float* w1      = (const float*)d_in[8];
    const float* b1      = (const float*)d_in[9];
    const float* ln1w    = (const float*)d_in[10];
    const float* ln1b    = (const float*)d_in[11];
    const float* w2      = (const float*)d_in[12];
    const float* b2      = (const float*)d_in[13];
    const float* ln2w    = (const float*)d_in[14];
    const float* ln2b    = (const float*)d_in[15];
    float* out = (float*)d_out;

    const int B = in_sizes[2];
    const int L = in_sizes[0] / B;

    hipLaunchKernelGGL(prep_kernel, dim3(32), dim3(256), 0, stream,
                       w1, w2, emb, b1, tp_w, tp_b, (unsigned*)d_ws);
    hipLaunchKernelGGL(encoder_mfma, dim3((B + 2) / 3), dim3(768), 0, stream,
                       tids, dates, lengths, tp_w, tp_b, tp_lnw, tp_lnb,
                       b1, ln1w, ln1b, b2, ln2w, ln2b,
                       (const unsigned*)d_ws, out, B, L);
}

// Round 15
// 191.123 us; speedup vs baseline: 1.1890x; 1.0214x over previous
//
#include <hip/hip_runtime.h>
#include <cmath>

#define LN_EPS 1e-5f

typedef float  f32x4  __attribute__((ext_vector_type(4)));
typedef float  f32x2  __attribute__((ext_vector_type(2)));
typedef short  short8 __attribute__((ext_vector_type(8)));
typedef unsigned int uint4v __attribute__((ext_vector_type(4)));

// ws layout (uint4 units):
//   w1tf : 512   (temporal K-slice of w1, k=128..159, B-frag layout, bf16)
//   w2f  : 2048  (B-frag layout, bf16)
//   E1   : 2450  (50 x 196 f32, PERMUTED [t][c][nt]: E1p[t*196 + c*12 + nt]
//                 holds (emb@w1[:128] + b1)[t][nt*16+c]; c-stride 12 floats
//                 (48 B, 16B-aligned, 2-way-max banking), row-stride 196)
//   tps  : 5 floats (uniform temporal-LN closed-form sums)
// E1 (round 10): only 50 distinct embedding rows -> emb@w1[:128] is a table
// (exact f32, b1 folded in r14). ROUND 15: permuted layout makes the per-tile
// gather 2x ds_read_b128 per r (8/tile, was 32 b32) and conflict-free.
#define W1TF_U4 512
#define W2F_U4  2048
#define E1_U4   2450
#define WLDS_U4 2560   // w1tf + w2f staged to LDS

__device__ __forceinline__ unsigned short f32_bf16_rne(float f) {
    union { float f; unsigned u; } v; v.f = f;
    unsigned r = v.u + 0x7FFFu + ((v.u >> 16) & 1u);
    return (unsigned short)(r >> 16);
}

// packed f32->bf16 (RNE), 1 VALU op for 2 elements
__device__ __forceinline__ unsigned cvt_pk_bf16(float lo, float hi) {
    unsigned r;
    asm("v_cvt_pk_bf16_f32 %0, %1, %2" : "=v"(r) : "v"(lo), "v"(hi));
    return r;
}

// GELU, tanh/sigmoid form (round 14): x * sigmoid(1.5957691*(x+0.044715x^3)).
// |err| vs exact-erf <= ~3e-4 absolute; bf16 rounding of the result dominates.
__device__ __forceinline__ float gelu_f(float x) {
    const float arg = x * fmaf(x * x, 0.044715f, 1.0f);   // x + 0.044715 x^3
    const float e   = __builtin_amdgcn_exp2f(arg * -2.302258f); // exp(-1.59577*arg)
    const float r   = __builtin_amdgcn_rcpf(e + 1.0f);    // sigmoid
    return x * r;
}

// DPP row-rotate add: sum over the 16-lane DPP row, all lanes get the result.
template<int C>
__device__ __forceinline__ float dpp_radd(float x) {
    int t = __builtin_amdgcn_update_dpp(0, __builtin_bit_cast(int, x), C, 0xF, 0xF, true);
    return x + __builtin_bit_cast(float, t);
}
__device__ __forceinline__ float red16(float x) {
    x = dpp_radd<0x128>(x);   // row_ror:8
    x = dpp_radd<0x124>(x);   // row_ror:4
    x = dpp_radd<0x122>(x);   // row_ror:2
    x = dpp_radd<0x121>(x);   // row_ror:1
    return x;
}

// -------- prep: build w1tf/w2f B-frags (bf16), E1p table (f32, permuted,
//          +b1), temporal-LN sums. Re-run every call.
__global__ void prep_kernel(const float* __restrict__ w1, const float* __restrict__ w2,
                            const float* __restrict__ emb, const float* __restrict__ b1,
                            const float* __restrict__ tp_w, const float* __restrict__ tp_b,
                            unsigned* __restrict__ ws) {
    const int tid = blockIdx.x * 256 + threadIdx.x;   // 8192 threads
    uint4v* w1tf = (uint4v*)ws;
    uint4v* w2f  = w1tf + W1TF_U4;
    float*  E1   = (float*)(w2f + W2F_U4);
    float*  tps  = E1 + 9800;                          // 50*196

    for (int i = tid; i < W1TF_U4; i += 8192) {       // temporal slice frags
        const int lane = i & 63, nt = i >> 6;         // nt 0..7
        const int k0 = 128 + (lane >> 4) * 8, n = nt * 16 + (lane & 15);
        uint4v r;
        #pragma unroll
        for (int j2 = 0; j2 < 4; ++j2) {
            unsigned lo = f32_bf16_rne(w1[(k0 + 2 * j2) * 128 + n]);
            unsigned hi = f32_bf16_rne(w1[(k0 + 2 * j2 + 1) * 128 + n]);
            r[j2] = lo | (hi << 16);
        }
        w1tf[i] = r;
    }
    for (int i = tid; i < W2F_U4; i += 8192) {
        const int lane = i & 63, nt = (i >> 6) & 7, kt = i >> 9;
        const int k0 = kt * 32 + (lane >> 4) * 8, n = nt * 16 + (lane & 15);
        uint4v r;
        #pragma unroll
        for (int j2 = 0; j2 < 4; ++j2) {
            unsigned lo = f32_bf16_rne(w2[(k0 + 2 * j2) * 128 + n]);
            unsigned hi = f32_bf16_rne(w2[(k0 + 2 * j2 + 1) * 128 + n]);
            r[j2] = lo | (hi << 16);
        }
        w2f[i] = r;
    }
    // E1p[t][c][nt] = b1[n] + sum_k emb[t][k]*w1[k][n], n = nt*16+c
    if (tid < 6400) {
        const int t = tid >> 7, n = tid & 127;
        float s = b1[n];
        #pragma unroll 4
        for (int k = 0; k < 128; ++k)
            s = fmaf(emb[t * 128 + k], w1[k * 128 + n], s);
        E1[t * 196 + (n & 15) * 12 + (n >> 4)] = s;
    }
    if (tid == 0) {                                   // uniform temporal-LN sums
        float Sw = 0.f, Sb = 0.f, Sww = 0.f, Swb = 0.f, Sbb = 0.f;
        for (int j = 0; j < 32; ++j) {
            const float ww = tp_w[j], bb = tp_b[j];
            Sw += ww; Sb += bb; Sww += ww * ww; Swb += ww * bb; Sbb += bb * bb;
        }
        tps[0] = Sw; tps[1] = Sb; tps[2] = Sww; tps[3] = Swb; tps[4] = Sbb;
    }
}

// -------- main: 768 threads = 12 waves; THREE batch rows per block, flattened
//          tile list (r11): wave w takes t = w, w+12, ... Pools in three NAMED
//          register arrays; per-wave partials -> poolbuf[3][12][128].
//
// REGIME (r12/r13/r14): VALU-work-stream bound. r15 work-cuts: E1 gather as
// 2x ds_read_b128/r (permuted table); b2 folded into acc2 C-init (hoisted
// b2c[8]); epi2 pooling linearized (A[nt] += msk*rstd*v per r + 3-op combine
// per nt at tile end); next-tile idr/d software prefetch hides global latency.
//
// REGISTER DISCIPLINE (rounds 2-5,7): (768,3) = 170-reg budget; r14 measured
// 68 arch + 64 acc. r15 adds b2c(8) + prefetch(5) + A(8 transient) ~= 90 arch
// peak. Phases strictly serial per tile; empty-asm fences only.
// SPILL TRIPWIRE: WRITE_SIZE > 50 MB => revert to r14.
__global__ __launch_bounds__(768, 3) void encoder_mfma(
    const int*   __restrict__ tids,  const float* __restrict__ dates,
    const int*   __restrict__ lengths,
    const float* __restrict__ tp_w,  const float* __restrict__ tp_b,
    const float* __restrict__ tp_lnw,const float* __restrict__ tp_lnb,
    const float* __restrict__ b1,    const float* __restrict__ ln1w, const float* __restrict__ ln1b,
    const float* __restrict__ b2,    const float* __restrict__ ln2w, const float* __restrict__ ln2b,
    const unsigned* __restrict__ ws, float* __restrict__ out,
    int B, int L)
{
    __shared__ __align__(16) uint4v wlds[WLDS_U4];                // 40 KB: w1tf|w2f
    __shared__ __align__(16) float  E1lds[9800];                  // 38.3 KB (permuted)
    // per-wave C->A transpose scratch (single m-tile): [wave][kt2][row64][j]
    __shared__ __align__(16) unsigned short a2[12][4][64][8];     // 48 KB
    __shared__ float poolbuf[3][12][128];                         // 18 KB
    __shared__ __align__(16) f32x4 tcoef[32];    // {tp_w, tp_b, tp_lnw, tp_lnb}
    __shared__ __align__(16) f32x4 ecoef1[128];  // {-, ln1w, ln1b, -} (b1 in E1)
    __shared__ __align__(8)  f32x2 ecoef2[128];  // {ln2w, ln2b} (b2 in acc2-init)

    const int tid = threadIdx.x;
    const int lane = tid & 63, w = tid >> 6;          // w in 0..11
    const int c = lane & 15, g = lane >> 4;
    const int b0 = blockIdx.x * 3;

    // ---- stage weights + E1 into LDS ----
    for (int i = tid; i < WLDS_U4; i += 768)
        wlds[i] = ((const uint4v*)ws)[i];
    for (int i = tid; i < E1_U4; i += 768)
        ((uint4v*)E1lds)[i] = ((const uint4v*)ws)[WLDS_U4 + i];

    const float* tps = (const float*)((const uint4v*)ws + WLDS_U4 + E1_U4);

    if (tid < 32)  tcoef[tid]  = (f32x4){tp_w[tid], tp_b[tid], tp_lnw[tid], tp_lnb[tid]};
    if (tid < 128) {
        ecoef1[tid] = (f32x4){0.f, ln1w[tid], ln1b[tid], 0.f};
        ecoef2[tid] = (f32x2){ln2w[tid], ln2b[tid]};
    }
    // hoisted per-lane b2 (acc2 C-init values)
    float b2c[8];
    #pragma unroll
    for (int nt = 0; nt < 8; ++nt) b2c[nt] = b2[nt * 16 + c];
    __syncthreads();

    const float Sw = tps[0], Sb = tps[1], Sww = tps[2], Swb = tps[3], Sbb = tps[4];

    // flattened tile list over the block's 3 rows
    const int len0 = (b0 + 0 < B) ? min(max(lengths[b0 + 0], 0), L) : 0;
    const int len1 = (b0 + 1 < B) ? min(max(lengths[b0 + 1], 0), L) : 0;
    const int len2 = (b0 + 2 < B) ? min(max(lengths[b0 + 2], 0), L) : 0;
    const int nt0 = (len0 + 15) >> 4, nt1 = (len1 + 15) >> 4, nt2 = (len2 + 15) >> 4;
    const int cum1 = nt0, cum2 = nt0 + nt1, T = cum2 + nt2;

    float pool0[8], pool1[8], pool2[8];
    #pragma unroll
    for (int nt = 0; nt < 8; ++nt) { pool0[nt] = 0.f; pool1[nt] = 0.f; pool2[nt] = 0.f; }
    const int srl = lane ^ ((lane >> 3) & 3);          // swizzled GEMM2 read row

    // ---- software-pipelined per-tile inputs (prefetched one tile ahead) ----
    int pidr[4]; float pd = 0.f;
    if (w < T) {
        const int row0 = (w >= cum2) ? 2 : ((w >= cum1) ? 1 : 0);
        const int tl0  = w - ((row0 == 2) ? cum2 : ((row0 == 1) ? cum1 : 0));
        const long bs0 = (long)(b0 + row0) * L;
        const int R00  = tl0 << 4;
        pd = dates[bs0 + min(R00 + c, L - 1)] * (1.f / 1825.f);
        #pragma unroll
        for (int r = 0; r < 4; ++r)
            pidr[r] = tids[bs0 + min(R00 + 4 * g + r, L - 1)];
    }

    for (int t = w; t < T; t += 12) {
        // wave-uniform (row, local tile) from flattened index
        const int row  = (t >= cum2) ? 2 : ((t >= cum1) ? 1 : 0);
        const int tl   = t - ((row == 2) ? cum2 : ((row == 1) ? cum1 : 0));
        const int lenr = (row == 2) ? len2 : ((row == 1) ? len1 : len0);
        const int R0   = tl << 4;

        int idr[4];
        #pragma unroll
        for (int r = 0; r < 4; ++r) idr[r] = pidr[r];
        const float d = pd;

        // ---- GEMM1 acc init: E1p gather, 2x ds_read_b128 per r ----
        f32x4 acc[8];
        #pragma unroll
        for (int r = 0; r < 4; ++r) {
            const float* p = &E1lds[idr[r] * 196 + c * 12];
            const f32x4 lo = *(const f32x4*)p;
            const f32x4 hi = *(const f32x4*)(p + 4);
            acc[0][r] = lo[0]; acc[1][r] = lo[1]; acc[2][r] = lo[2]; acc[3][r] = lo[3];
            acc[4][r] = hi[0]; acc[5][r] = hi[1]; acc[6][r] = hi[2]; acc[7][r] = hi[3];
        }

        // temporal A-frag (row = c, k-chunk = g*8..g*8+7); coeffs from LDS
        short8 tfrag;
        {
            const float tm = fmaf(d, Sw, Sb) * (1.f / 32.f);
            float tv = fmaf(d * d, Sww, fmaf(2.f * d, Swb, Sbb)) * (1.f / 32.f) - tm * tm;
            const float trs = rsqrtf(fmaxf(tv, 0.f) + LN_EPS);
            const int j0 = g * 8;
            uint4v r;
            #pragma unroll
            for (int j2 = 0; j2 < 4; ++j2) {
                const f32x4 t0 = tcoef[j0 + 2*j2];
                const f32x4 t1 = tcoef[j0 + 2*j2 + 1];
                const float y0 = fmaf((fmaf(d, t0[0], t0[1]) - tm) * trs, t0[2], t0[3]);
                const float y1 = fmaf((fmaf(d, t1[0], t1[1]) - tm) * trs, t1[2], t1[3]);
                r[j2] = cvt_pk_bf16(gelu_f(y0), gelu_f(y1));
            }
            union { uint4v u; short8 s; } cv; cv.u = r;
            tfrag = cv.s;
        }

        // ---- GEMM1: temporal K=32 slice ----
        __builtin_amdgcn_s_setprio(1);
        #pragma unroll
        for (int nt = 0; nt < 8; ++nt) {
            const short8 bf = ((const short8*)wlds)[nt * 64 + lane];
            acc[nt] = __builtin_amdgcn_mfma_f32_16x16x32_bf16(tfrag, bf, acc[nt], 0, 0, 0);
        }
        __builtin_amdgcn_s_setprio(0);

        // ---- prefetch NEXT tile's inputs (loads land during epi1/GEMM2) ----
        {
            const int tn = t + 12;
            if (tn < T) {
                const int rowN = (tn >= cum2) ? 2 : ((tn >= cum1) ? 1 : 0);
                const int tlN  = tn - ((rowN == 2) ? cum2 : ((rowN == 1) ? cum1 : 0));
                const long bsN = (long)(b0 + rowN) * L;
                const int R0N  = tlN << 4;
                pd = dates[bsN + min(R0N + c, L - 1)] * (1.f / 1825.f);
                #pragma unroll
                for (int r = 0; r < 4; ++r)
                    pidr[r] = tids[bsN + min(R0N + 4 * g + r, L - 1)];
            }
        }

        // ------- epilogue 1: LN1 (DPP), GELU -> bf16 a2[w] (swizzled) -------
        {
            f32x4 e1[8];
            #pragma unroll
            for (int nt = 0; nt < 8; ++nt) e1[nt] = ecoef1[nt * 16 + c];
            #pragma unroll
            for (int r = 0; r < 4; ++r) {
                float v[8], s = 0.f, q = 0.f;
                #pragma unroll
                for (int nt = 0; nt < 8; ++nt) {
                    v[nt] = acc[nt][r];                // b1 already in E1
                    s += v[nt]; q = fmaf(v[nt], v[nt], q);
                }
                s = red16(s); q = red16(q);
                const float mean = s * (1.f / 128.f);
                const float var  = fmaxf(q * (1.f / 128.f) - mean * mean, 0.f);
                const float rstd = rsqrtf(var + LN_EPS);
                const int mrow = 4 * g + r;
                #pragma unroll
                for (int n2 = 0; n2 < 4; ++n2) {
                    const float y0 = gelu_f(fmaf((v[2*n2]   - mean) * rstd, e1[2*n2][1],   e1[2*n2][2]));
                    const float y1 = gelu_f(fmaf((v[2*n2+1] - mean) * rstd, e1[2*n2+1][1], e1[2*n2+1][2]));
                    const unsigned pk = cvt_pk_bf16(y0, y1);
                    {
                        const int kcol  = (2*n2) * 16 + c;
                        const int row64 = ((kcol >> 3) & 3) * 16 + mrow;
                        const int srow  = row64 ^ ((row64 >> 3) & 3);
                        a2[w][kcol >> 5][srow][kcol & 7] = (unsigned short)(pk & 0xffffu);
                    }
                    {
                        const int kcol  = (2*n2+1) * 16 + c;
                        const int row64 = ((kcol >> 3) & 3) * 16 + mrow;
                        const int srow  = row64 ^ ((row64 >> 3) & 3);
                        a2[w][kcol >> 5][srow][kcol & 7] = (unsigned short)(pk >> 16);
                    }
                }
            }
        }

        asm volatile("" ::: "memory");                 // order a2 W->R (DS in-order)

        // ---------------- GEMM2: a2[w] @ w2f(LDS); C-init = b2 ----------------
        f32x4 acc2[8];
        #pragma unroll
        for (int nt = 0; nt < 8; ++nt)
            acc2[nt] = (f32x4){b2c[nt], b2c[nt], b2c[nt], b2c[nt]};
        __builtin_amdgcn_s_setprio(1);
        #pragma unroll
        for (int kt2 = 0; kt2 < 4; ++kt2) {
            short8 af;
            __builtin_memcpy(&af, &a2[w][kt2][srl][0], 16);
            #pragma unroll
            for (int nt = 0; nt < 8; ++nt) {
                const short8 bf = ((const short8*)(wlds + W1TF_U4))[(kt2 * 8 + nt) * 64 + lane];
                acc2[nt] = __builtin_amdgcn_mfma_f32_16x16x32_bf16(af, bf, acc2[nt], 0, 0, 0);
            }
        }
        __builtin_amdgcn_s_setprio(0);

        asm volatile("" ::: "memory");                 // order a2 R -> next tile W

        // ------- epilogue 2 (linearized): LN2+mask+pool via A/Sb/Sg -------
        //   pool[nt] += l2w*(A[nt]-Sb) + l2b*Sg, A[nt] = sum_r msk*rstd*v[nt][r]
        {
            float A[8], Sbv = 0.f, Sgv = 0.f;
            #pragma unroll
            for (int nt = 0; nt < 8; ++nt) A[nt] = 0.f;
            #pragma unroll
            for (int r = 0; r < 4; ++r) {
                float s = 0.f, q = 0.f;
                #pragma unroll
                for (int nt = 0; nt < 8; ++nt) {
                    const float v = acc2[nt][r];       // b2 already in C-init
                    s += v; q = fmaf(v, v, q);
                }
                s = red16(s); q = red16(q);
                const float mean = s * (1.f / 128.f);
                const float var  = fmaxf(q * (1.f / 128.f) - mean * mean, 0.f);
                const float rstd = rsqrtf(var + LN_EPS);
                const float msk  = ((R0 + 4 * g + r) < lenr) ? 1.f : 0.f;
                const float alf  = msk * rstd;
                Sbv = fmaf(alf, mean, Sbv);
                Sgv += msk;
                #pragma unroll
                for (int nt = 0; nt < 8; ++nt)
                    A[nt] = fmaf(acc2[nt][r], alf, A[nt]);
            }
            if (row == 0) {
                #pragma unroll
                for (int nt = 0; nt < 8; ++nt) {
                    const f32x2 e = ecoef2[nt * 16 + c];
                    pool0[nt] = fmaf(e[0], A[nt] - Sbv, fmaf(e[1], Sgv, pool0[nt]));
                }
            } else if (row == 1) {
                #pragma unroll
                for (int nt = 0; nt < 8; ++nt) {
                    const f32x2 e = ecoef2[nt * 16 + c];
                    pool1[nt] = fmaf(e[0], A[nt] - Sbv, fmaf(e[1], Sgv, pool1[nt]));
                }
            } else {
                #pragma unroll
                for (int nt = 0; nt < 8; ++nt) {
                    const f32x2 e = ecoef2[nt * 16 + c];
                    pool2[nt] = fmaf(e[0], A[nt] - Sbv, fmaf(e[1], Sgv, pool2[nt]));
                }
            }
        }
    }

    // wave-level pool reduce (over g groups), then cross-wave combine in LDS
    #pragma unroll
    for (int nt = 0; nt < 8; ++nt) {
        float t0 = pool0[nt]; t0 += __shfl_xor(t0, 16); t0 += __shfl_xor(t0, 32); pool0[nt] = t0;
        float t1 = pool1[nt]; t1 += __shfl_xor(t1, 16); t1 += __shfl_xor(t1, 32); pool1[nt] = t1;
        float t2 = pool2[nt]; t2 += __shfl_xor(t2, 16); t2 += __shfl_xor(t2, 32); pool2[nt] = t2;
    }
    if (g == 0) {
        #pragma unroll
        for (int nt = 0; nt < 8; ++nt) {
            poolbuf[0][w][nt * 16 + c] = pool0[nt];
            poolbuf[1][w][nt * 16 + c] = pool1[nt];
            poolbuf[2][w][nt * 16 + c] = pool2[nt];
        }
    }
    __syncthreads();
    if (tid < 384) {
        const int r3  = tid >> 7;                      // which row of the triple
        const int col = tid & 127;
        const int bo  = b0 + r3;
        if (bo < B) {
            const int lenb = min(max(lengths[bo], 0), L);
            float s = 0.f;
            #pragma unroll
            for (int k = 0; k < 12; ++k) s += poolbuf[r3][k][col];
            out[bo * 128 + col] = (lenb > 0) ? s / (float)lenb : 0.f;
        }
    }
}

extern "C" void kernel_launch(void* const* d_in, const int* in_sizes, int n_in,
                              void* d_out, int out_size, void* d_ws, size_t ws_size,
                              hipStream_t stream) {
    const int*   tids    = (const int*)  d_in[0];
    const float* dates   = (const float*)d_in[1];
    const int*   lengths = (const int*)  d_in[2];
    const float* emb     = (const float*)d_in[3];
    const float* tp_w    = (const float*)d_in[4];
    const float* tp_b    = (const float*)d_in[5];
    const float* tp_lnw  = (const float*)d_in[6];
    const float* tp_lnb  = (const float*)d_in[7];
    const float* w1      = (const float*)d_in[8];
    const float* b1      = (const float*)d_in[9];
    const float* ln1w    = (const float*)d_in[10];
    const float* ln1b    = (const float*)d_in[11];
    const float* w2      = (const float*)d_in[12];
    const float* b2      = (const float*)d_in[13];
    const float* ln2w    = (const float*)d_in[14];
    const float* ln2b    = (const float*)d_in[15];
    float* out = (float*)d_out;

    const int B = in_sizes[2];
    const int L = in_sizes[0] / B;

    hipLaunchKernelGGL(prep_kernel, dim3(32), dim3(256), 0, stream,
                       w1, w2, emb, b1, tp_w, tp_b, (unsigned*)d_ws);
    hipLaunchKernelGGL(encoder_mfma, dim3((B + 2) / 3), dim3(768), 0, stream,
                       tids, dates, lengths, tp_w, tp_b, tp_lnw, tp_lnb,
                       b1, ln1w, ln1b, b2, ln2w, ln2b,
                       (const unsigned*)d_ws, out, B, L);
}